// Round 1
// baseline (6000.211 us; speedup 1.0000x reference)
//
#include <hip/hip_runtime.h>
#include <hip/hip_bf16.h>

#define B_   16
#define T_   32
#define N_   512
#define C_   128
#define H_   128
#define HL_  512
#define G4_  2048
#define D_   65536
#define BT_  512
#define TNH_ 2097152   // T*N*H
#define EPS_ 1e-5f

static __device__ __forceinline__ float sigmoidf_(float x) {
  return 1.f / (1.f + __expf(-x));
}

// ---------------- degree + normalized adjacency ----------------
__global__ void k_deg(const float* __restrict__ adj, float* __restrict__ dv) {
  int i = blockIdx.x;
  int lane = threadIdx.x;              // 64
  const float* row = adj + (long)i * N_;
  float s = 0.f;
  for (int j = lane; j < N_; j += 64) s += row[j];
  #pragma unroll
  for (int off = 32; off > 0; off >>= 1) s += __shfl_down(s, off, 64);
  if (lane == 0) dv[i] = rsqrtf(s + 1.f);   // +1 for self-loop
}

__global__ void k_mnorm(const float* __restrict__ adj, const float* __restrict__ dv,
                        float* __restrict__ M) {
  int idx = blockIdx.x * 256 + threadIdx.x;   // 262144
  int i = idx >> 9, j = idx & (N_ - 1);
  float a = adj[idx] + ((i == j) ? 1.f : 0.f);
  M[idx] = dv[i] * a * dv[j];
}

// ---------------- tiled fp32 GEMM (NN): C[bt] = A[bt] * B[bt/t] ----------------
// BM=BN=128, BK=16; 256 threads; each thread 8x8.
// NOTE: out may alias A (in-place row-wise GEMM): each block reads only its own
// 128 rows during the K loop and writes them only in the epilogue, so no
// cross-block or read-after-write hazard exists. Hence NO __restrict__ here.
#define GBM 128
#define GBN 128
#define GBK 16

__global__ __launch_bounds__(256, 2)
void k_gemm_nn(float* out,
               const float* A, long aStrideBT, int lda,
               const float* __restrict__ Bsrc, long bStrideBT, long bStrideT,
               const float* __restrict__ bias,   // per-t bias[t*H_] or nullptr
               int K)
{
  __shared__ float As[GBK][GBM + 4];
  __shared__ float Bs[GBK][GBN + 4];
  int mt = blockIdx.x;
  int bt = blockIdx.y;
  int t  = bt & (T_ - 1);
  const float* Ap = A + (long)bt * aStrideBT + (long)mt * GBM * lda;
  const float* Bp = Bsrc + (long)bt * bStrideBT + (long)t * bStrideT;
  float* Cp = out + ((long)bt * N_ + (long)mt * GBM) * H_;

  int tid = threadIdx.x;
  int tx = tid & 15, ty = tid >> 4;
  int am = tid >> 1, ak = (tid & 1) * 8;       // A stage: row am, k-offset ak
  int br = tid >> 4, bc = (tid & 15) * 8;      // B stage: row br, col bc

  float acc[8][8];
  #pragma unroll
  for (int i = 0; i < 8; ++i)
    #pragma unroll
    for (int j = 0; j < 8; ++j) acc[i][j] = 0.f;

  for (int k0 = 0; k0 < K; k0 += GBK) {
    float4 a0 = *(const float4*)(Ap + (long)am * lda + k0 + ak);
    float4 a1 = *(const float4*)(Ap + (long)am * lda + k0 + ak + 4);
    float4 b0 = *(const float4*)(Bp + (long)(k0 + br) * H_ + bc);
    float4 b1 = *(const float4*)(Bp + (long)(k0 + br) * H_ + bc + 4);
    As[ak+0][am] = a0.x; As[ak+1][am] = a0.y; As[ak+2][am] = a0.z; As[ak+3][am] = a0.w;
    As[ak+4][am] = a1.x; As[ak+5][am] = a1.y; As[ak+6][am] = a1.z; As[ak+7][am] = a1.w;
    *(float4*)&Bs[br][bc]     = b0;
    *(float4*)&Bs[br][bc + 4] = b1;
    __syncthreads();
    #pragma unroll
    for (int kk = 0; kk < GBK; ++kk) {
      float a[8], b[8];
      *(float4*)&a[0] = *(const float4*)&As[kk][ty * 8];
      *(float4*)&a[4] = *(const float4*)&As[kk][ty * 8 + 4];
      *(float4*)&b[0] = *(const float4*)&Bs[kk][tx * 8];
      *(float4*)&b[4] = *(const float4*)&Bs[kk][tx * 8 + 4];
      #pragma unroll
      for (int i = 0; i < 8; ++i)
        #pragma unroll
        for (int j = 0; j < 8; ++j)
          acc[i][j] = fmaf(a[i], b[j], acc[i][j]);
    }
    __syncthreads();
  }
  float bv[8] = {0,0,0,0,0,0,0,0};
  if (bias) {
    const float* bp2 = bias + (long)t * H_ + tx * 8;
    #pragma unroll
    for (int j = 0; j < 8; ++j) bv[j] = bp2[j];
  }
  #pragma unroll
  for (int i = 0; i < 8; ++i) {
    float* dst = Cp + (long)(ty * 8 + i) * H_ + tx * 8;
    float4 r0 = make_float4(acc[i][0]+bv[0], acc[i][1]+bv[1], acc[i][2]+bv[2], acc[i][3]+bv[3]);
    float4 r1 = make_float4(acc[i][4]+bv[4], acc[i][5]+bv[5], acc[i][6]+bv[6], acc[i][7]+bv[7]);
    *(float4*)dst       = r0;
    *(float4*)(dst + 4) = r1;
  }
}

// ---------------- NT GEMM, deterministic split-K (partials, no atomics) ------
// part[kc][512][2048] = A[512][K]~chunk kc  *  B[2048][K]^T~chunk kc
// grid = 4 mt * 16 nt * NCHUNK kc  (kc = bx>>6)
__global__ __launch_bounds__(256, 2)
void k_gemm_nt_splitk(float* __restrict__ part,
                      const float* __restrict__ A, int lda,
                      const float* __restrict__ Bt, int ldb,
                      int Kchunk)
{
  __shared__ float As[GBK][GBM + 4];
  __shared__ float Bs[GBK][GBN + 4];
  int bx = blockIdx.x;
  int mt = bx & 3;           // 512/128
  int nt = (bx >> 2) & 15;   // 2048/128
  int kc = bx >> 6;
  const float* Ap = A  + (long)mt * GBM * lda + (long)kc * Kchunk;
  const float* Bp = Bt + (long)nt * GBN * ldb + (long)kc * Kchunk;

  int tid = threadIdx.x;
  int tx = tid & 15, ty = tid >> 4;
  int am = tid >> 1, ak = (tid & 1) * 8;

  float acc[8][8];
  #pragma unroll
  for (int i = 0; i < 8; ++i)
    #pragma unroll
    for (int j = 0; j < 8; ++j) acc[i][j] = 0.f;

  for (int k0 = 0; k0 < Kchunk; k0 += GBK) {
    float4 a0 = *(const float4*)(Ap + (long)am * lda + k0 + ak);
    float4 a1 = *(const float4*)(Ap + (long)am * lda + k0 + ak + 4);
    float4 b0 = *(const float4*)(Bp + (long)am * ldb + k0 + ak);
    float4 b1 = *(const float4*)(Bp + (long)am * ldb + k0 + ak + 4);
    As[ak+0][am] = a0.x; As[ak+1][am] = a0.y; As[ak+2][am] = a0.z; As[ak+3][am] = a0.w;
    As[ak+4][am] = a1.x; As[ak+5][am] = a1.y; As[ak+6][am] = a1.z; As[ak+7][am] = a1.w;
    Bs[ak+0][am] = b0.x; Bs[ak+1][am] = b0.y; Bs[ak+2][am] = b0.z; Bs[ak+3][am] = b0.w;
    Bs[ak+4][am] = b1.x; Bs[ak+5][am] = b1.y; Bs[ak+6][am] = b1.z; Bs[ak+7][am] = b1.w;
    __syncthreads();
    #pragma unroll
    for (int kk = 0; kk < GBK; ++kk) {
      float a[8], b[8];
      *(float4*)&a[0] = *(const float4*)&As[kk][ty * 8];
      *(float4*)&a[4] = *(const float4*)&As[kk][ty * 8 + 4];
      *(float4*)&b[0] = *(const float4*)&Bs[kk][tx * 8];
      *(float4*)&b[4] = *(const float4*)&Bs[kk][tx * 8 + 4];
      #pragma unroll
      for (int i = 0; i < 8; ++i)
        #pragma unroll
        for (int j = 0; j < 8; ++j)
          acc[i][j] = fmaf(a[i], b[j], acc[i][j]);
    }
    __syncthreads();
  }
  float* base = part + (long)kc * (BT_ * G4_);
  #pragma unroll
  for (int i = 0; i < 8; ++i) {
    float* dst = base + (long)(mt * GBM + ty * 8 + i) * G4_ + nt * GBN + tx * 8;
    float4 r0 = make_float4(acc[i][0], acc[i][1], acc[i][2], acc[i][3]);
    float4 r1 = make_float4(acc[i][4], acc[i][5], acc[i][6], acc[i][7]);
    *(float4*)dst       = r0;
    *(float4*)(dst + 4) = r1;
  }
}

__global__ void k_reduce_gates(float* __restrict__ G, const float* __restrict__ part,
                               const float* __restrict__ b1, const float* __restrict__ b2,
                               int nchunk) {
  int idx = blockIdx.x * 256 + threadIdx.x;   // 512*2048
  int g = idx & (G4_ - 1);
  float s = b1[g] + b2[g];
  for (int p = 0; p < nchunk; ++p) s += part[(long)p * (BT_ * G4_) + idx];
  G[idx] = s;
}

// ---------------- GraphNorm (+ residual + ReLU), stats over B=16 ----------------
// out may alias pre (read-complete-before-write per thread; threads own disjoint idx).
__global__ __launch_bounds__(256)
void k_graphnorm(float* out, const float* pre, const float* resid,
                 const float* __restrict__ wgt, const float* __restrict__ bias,
                 const float* __restrict__ ms)
{
  int idx = blockIdx.x * 256 + threadIdx.x;   // over T*N*H
  int h = idx & 127;
  float v[16];
  float mean = 0.f;
  #pragma unroll
  for (int bb = 0; bb < 16; ++bb) { v[bb] = pre[(long)bb * TNH_ + idx]; mean += v[bb]; }
  mean *= (1.f / 16.f);
  float msh = ms[h];
  float var = 0.f;
  #pragma unroll
  for (int bb = 0; bb < 16; ++bb) { v[bb] -= msh * mean; var += v[bb] * v[bb]; }
  var *= (1.f / 16.f);
  float sc = wgt[h] * rsqrtf(var + EPS_);
  float bh = bias[h];
  #pragma unroll
  for (int bb = 0; bb < 16; ++bb) {
    float r = sc * v[bb] + bh + resid[(long)bb * TNH_ + idx];
    out[(long)bb * TNH_ + idx] = fmaxf(r, 0.f);
  }
}

// ---------------- LSTM ----------------
__global__ void k_transpose_whh(const float* __restrict__ W, float* __restrict__ WT) {
  int idx = blockIdx.x * 256 + threadIdx.x;   // 512*2048
  int k = idx >> 11, g = idx & (G4_ - 1);
  WT[idx] = W[(long)g * HL_ + k];             // WT[k][g] = W[g][k]
}

// One block per batch element; all 32 recurrent steps inside one kernel.
// 512 threads: thread tid handles gate g = tid>>7, columns jq..jq+3 (jq = (tid&127)*4).
// h(t-1) lives in LDS (hs), gate pre-activations staged in LDS (gs),
// c lives in registers of threads tid<128 (4 lanes of c each).
// Weight reads: WT[k][g*512+jq..+3] -> coalesced float4, L2-resident (4 MB).
__global__ __launch_bounds__(512)
void k_lstm_layer(const float* __restrict__ G,   // [B*T][2048] x-proj + bih + bhh
                  const float* __restrict__ WT,  // [512][2048]
                  float* __restrict__ y)         // [B][T][512]
{
  __shared__ float hs[HL_];
  __shared__ float gs[G4_];
  int b   = blockIdx.x;
  int tid = threadIdx.x;
  int g   = tid >> 7;
  int jq  = (tid & 127) << 2;
  const float* wp = WT + g * HL_ + jq;

  float c0 = 0.f, c1 = 0.f, c2 = 0.f, c3 = 0.f;   // used by tid<128 only
  hs[tid] = 0.f;
  __syncthreads();

  for (int t = 0; t < T_; ++t) {
    const float* g0 = G + ((long)b * T_ + t) * G4_;
    float4 acc = *(const float4*)(g0 + g * HL_ + jq);
    #pragma unroll 8
    for (int k = 0; k < HL_; ++k) {
      float hk = hs[k];
      float4 wv = *(const float4*)(wp + (long)k * G4_);
      acc.x = fmaf(hk, wv.x, acc.x);
      acc.y = fmaf(hk, wv.y, acc.y);
      acc.z = fmaf(hk, wv.z, acc.z);
      acc.w = fmaf(hk, wv.w, acc.w);
    }
    __syncthreads();                       // all hs reads of this step done
    *(float4*)&gs[g * HL_ + jq] = acc;
    __syncthreads();                       // gates visible
    if (tid < 128) {
      int j = tid << 2;
      float4 ai = *(const float4*)&gs[0 * HL_ + j];
      float4 af = *(const float4*)&gs[1 * HL_ + j];
      float4 ag = *(const float4*)&gs[2 * HL_ + j];
      float4 ao = *(const float4*)&gs[3 * HL_ + j];
      float h0, h1, h2, h3;
      c0 = sigmoidf_(af.x) * c0 + sigmoidf_(ai.x) * tanhf(ag.x);
      h0 = sigmoidf_(ao.x) * tanhf(c0);
      c1 = sigmoidf_(af.y) * c1 + sigmoidf_(ai.y) * tanhf(ag.y);
      h1 = sigmoidf_(ao.y) * tanhf(c1);
      c2 = sigmoidf_(af.z) * c2 + sigmoidf_(ai.z) * tanhf(ag.z);
      h2 = sigmoidf_(ao.z) * tanhf(c2);
      c3 = sigmoidf_(af.w) * c3 + sigmoidf_(ai.w) * tanhf(ag.w);
      h3 = sigmoidf_(ao.w) * tanhf(c3);
      float4 hv = make_float4(h0, h1, h2, h3);
      *(float4*)&hs[j] = hv;
      *(float4*)(y + ((long)b * T_ + t) * HL_ + j) = hv;
    }
    __syncthreads();                       // hs(t) ready for next step
  }
}

__global__ void k_final(const float* __restrict__ y1, const float* __restrict__ Wp,
                        const float* __restrict__ bp, float* __restrict__ out) {
  int tid = threadIdx.x;      // 128 = 16 b * 8 o
  int b = tid >> 3, o = tid & 7;
  const float* h = y1 + ((long)b * T_ + (T_ - 1)) * HL_;
  const float* w = Wp + (long)o * HL_;
  float s = bp[o];
  for (int k = 0; k < HL_; ++k) s = fmaf(h[k], w[k], s);
  out[b * 8 + o] = s;
}

// ---------------- launch ----------------
extern "C" void kernel_launch(void* const* d_in, const int* in_sizes, int n_in,
                              void* d_out, int out_size, void* d_ws, size_t ws_size,
                              hipStream_t stream)
{
  const float* x    = (const float*)d_in[0];
  const float* adj  = (const float*)d_in[1];
  const float* W1   = (const float*)d_in[2];
  const float* b1   = (const float*)d_in[3];
  const float* W2   = (const float*)d_in[4];
  const float* b2   = (const float*)d_in[5];
  const float* gn1w = (const float*)d_in[6];
  const float* gn1b = (const float*)d_in[7];
  const float* gn1m = (const float*)d_in[8];
  const float* gn2w = (const float*)d_in[9];
  const float* gn2b = (const float*)d_in[10];
  const float* gn2m = (const float*)d_in[11];
  const float* Wih0 = (const float*)d_in[12];
  const float* Whh0 = (const float*)d_in[13];
  const float* bih0 = (const float*)d_in[14];
  const float* bhh0 = (const float*)d_in[15];
  const float* Wih1 = (const float*)d_in[16];
  const float* Whh1 = (const float*)d_in[17];
  const float* bih1 = (const float*)d_in[18];
  const float* bhh1 = (const float*)d_in[19];
  const float* Wp   = (const float*)d_in[20];
  const float* bp   = (const float*)d_in[21];
  float* out = (float*)d_out;

  // -------- workspace layout: 70,009,344 floats = 280.0 MB total --------
  float* w = (float*)d_ws;
  float* Mn  = w; w += 262144;    // [N][N]
  float* dv  = w; w += 512;
  float* G0  = w; w += 1048576;   // [BT][2048]
  float* G1  = w; w += 1048576;
  float* y0  = w; w += 262144;    // [B][T][HL]
  float* y1  = w; w += 262144;
  float* c0  = w; w += 8192;      // (unused now; kept for layout stability)
  float* c1  = w; w += 8192;
  float* P   = w; w += 33554432;  // [B][T][N][H]
  float* Q   = w; w += 33554432;  // [B][T][N][H]
  (void)c0; (void)c1;
  // After the GCN stack completes, P (h1) is dead; reuse its space:
  float* Gp  = P;                 // up to [8][512][2048] split-K partials (32 MB)
  float* WT0 = P + 8388608;       // [512][2048]
  float* WT1 = P + 9437184;       // [512][2048]

  // graph prep
  k_deg<<<N_, 64, 0, stream>>>(adj, dv);
  k_mnorm<<<1024, 256, 0, stream>>>(adj, dv, Mn);

  // GCN layer 1 (reassociated: M@(X@W) == (M@X)@W):
  k_gemm_nn<<<dim3(4, BT_), 256, 0, stream>>>(P, Mn, 0L, N_, x, (long)N_*C_, 0L, nullptr, N_);
  k_gemm_nn<<<dim3(4, BT_), 256, 0, stream>>>(P, P, (long)N_*H_, C_, W1, 0L, (long)C_*H_, b1, C_);
  k_graphnorm<<<8192, 256, 0, stream>>>(P, P, x, gn1w, gn1b, gn1m);

  // GCN layer 2
  k_gemm_nn<<<dim3(4, BT_), 256, 0, stream>>>(Q, Mn, 0L, N_, P, (long)N_*H_, 0L, nullptr, N_);
  k_gemm_nn<<<dim3(4, BT_), 256, 0, stream>>>(Q, Q, (long)N_*H_, H_, W2, 0L, (long)H_*H_, b2, H_);
  k_graphnorm<<<8192, 256, 0, stream>>>(Q, Q, P, gn2w, gn2b, gn2m);
  // ---- P is now dead; Gp/WT0/WT1 live in its space from here on ----

  k_transpose_whh<<<4096, 256, 0, stream>>>(Whh0, WT0);
  k_transpose_whh<<<4096, 256, 0, stream>>>(Whh1, WT1);

  // LSTM layer 0: input projection (split-K x8 -> 512 blocks = 2/CU) + fused recurrence
  k_gemm_nt_splitk<<<512, 256, 0, stream>>>(Gp, Q, D_, Wih0, D_, D_ / 8);
  k_reduce_gates<<<4096, 256, 0, stream>>>(G0, Gp, bih0, bhh0, 8);
  k_lstm_layer<<<16, 512, 0, stream>>>(G0, WT0, y0);

  // LSTM layer 1
  k_gemm_nt_splitk<<<256, 256, 0, stream>>>(Gp, y0, HL_, Wih1, HL_, HL_ / 4);
  k_reduce_gates<<<4096, 256, 0, stream>>>(G1, Gp, bih1, bhh1, 4);
  k_lstm_layer<<<16, 512, 0, stream>>>(G1, WT1, y1);

  k_final<<<1, 128, 0, stream>>>(y1, Wp, bp, out);
}

// Round 2
// 4407.862 us; speedup vs baseline: 1.3613x; 1.3613x over previous
//
#include <hip/hip_runtime.h>

#define B_   16
#define T_   32
#define N_   512
#define C_   128
#define H_   128
#define HL_  512
#define G4_  2048
#define D_   65536
#define BT_  512
#define TNH_ 2097152   // T*N*H
#define EPS_ 1e-5f

typedef __bf16 bf16x8 __attribute__((ext_vector_type(8)));
typedef float  f32x4  __attribute__((ext_vector_type(4)));

static __device__ __forceinline__ float sigmoidf_(float x) {
  return 1.f / (1.f + __expf(-x));
}

// RNE fp32 -> bf16 (ignores NaN edge case; inputs are finite)
static __device__ __forceinline__ unsigned short f2bf_(float f) {
  unsigned u = __float_as_uint(f);
  u += 0x7fffu + ((u >> 16) & 1u);
  return (unsigned short)(u >> 16);
}
static __device__ __forceinline__ unsigned pk2_(float lo, float hi) {
  return (unsigned)f2bf_(lo) | ((unsigned)f2bf_(hi) << 16);
}

// ---------------- degree + normalized adjacency ----------------
__global__ void k_deg(const float* __restrict__ adj, float* __restrict__ dv) {
  int i = blockIdx.x;
  int lane = threadIdx.x;              // 64
  const float* row = adj + (long)i * N_;
  float s = 0.f;
  for (int j = lane; j < N_; j += 64) s += row[j];
  #pragma unroll
  for (int off = 32; off > 0; off >>= 1) s += __shfl_down(s, off, 64);
  if (lane == 0) dv[i] = rsqrtf(s + 1.f);   // +1 for self-loop
}

__global__ void k_mnorm(const float* __restrict__ adj, const float* __restrict__ dv,
                        float* __restrict__ M) {
  int idx = blockIdx.x * 256 + threadIdx.x;   // 262144
  int i = idx >> 9, j = idx & (N_ - 1);
  float a = adj[idx] + ((i == j) ? 1.f : 0.f);
  M[idx] = dv[i] * a * dv[j];
}

// ---------------- tiled fp32 GEMM (NN): C[bt] = A[bt] * B[bt/t] ----------------
#define GBM 128
#define GBN 128
#define GBK 16

__global__ __launch_bounds__(256, 2)
void k_gemm_nn(float* out,
               const float* A, long aStrideBT, int lda,
               const float* __restrict__ Bsrc, long bStrideBT, long bStrideT,
               const float* __restrict__ bias,   // per-t bias[t*H_] or nullptr
               int K)
{
  __shared__ float As[GBK][GBM + 4];
  __shared__ float Bs[GBK][GBN + 4];
  int mt = blockIdx.x;
  int bt = blockIdx.y;
  int t  = bt & (T_ - 1);
  const float* Ap = A + (long)bt * aStrideBT + (long)mt * GBM * lda;
  const float* Bp = Bsrc + (long)bt * bStrideBT + (long)t * bStrideT;
  float* Cp = out + ((long)bt * N_ + (long)mt * GBM) * H_;

  int tid = threadIdx.x;
  int tx = tid & 15, ty = tid >> 4;
  int am = tid >> 1, ak = (tid & 1) * 8;
  int br = tid >> 4, bc = (tid & 15) * 8;

  float acc[8][8];
  #pragma unroll
  for (int i = 0; i < 8; ++i)
    #pragma unroll
    for (int j = 0; j < 8; ++j) acc[i][j] = 0.f;

  for (int k0 = 0; k0 < K; k0 += GBK) {
    float4 a0 = *(const float4*)(Ap + (long)am * lda + k0 + ak);
    float4 a1 = *(const float4*)(Ap + (long)am * lda + k0 + ak + 4);
    float4 b0 = *(const float4*)(Bp + (long)(k0 + br) * H_ + bc);
    float4 b1 = *(const float4*)(Bp + (long)(k0 + br) * H_ + bc + 4);
    As[ak+0][am] = a0.x; As[ak+1][am] = a0.y; As[ak+2][am] = a0.z; As[ak+3][am] = a0.w;
    As[ak+4][am] = a1.x; As[ak+5][am] = a1.y; As[ak+6][am] = a1.z; As[ak+7][am] = a1.w;
    *(float4*)&Bs[br][bc]     = b0;
    *(float4*)&Bs[br][bc + 4] = b1;
    __syncthreads();
    #pragma unroll
    for (int kk = 0; kk < GBK; ++kk) {
      float a[8], b[8];
      *(float4*)&a[0] = *(const float4*)&As[kk][ty * 8];
      *(float4*)&a[4] = *(const float4*)&As[kk][ty * 8 + 4];
      *(float4*)&b[0] = *(const float4*)&Bs[kk][tx * 8];
      *(float4*)&b[4] = *(const float4*)&Bs[kk][tx * 8 + 4];
      #pragma unroll
      for (int i = 0; i < 8; ++i)
        #pragma unroll
        for (int j = 0; j < 8; ++j)
          acc[i][j] = fmaf(a[i], b[j], acc[i][j]);
    }
    __syncthreads();
  }
  float bv[8] = {0,0,0,0,0,0,0,0};
  if (bias) {
    const float* bp2 = bias + (long)t * H_ + tx * 8;
    #pragma unroll
    for (int j = 0; j < 8; ++j) bv[j] = bp2[j];
  }
  #pragma unroll
  for (int i = 0; i < 8; ++i) {
    float* dst = Cp + (long)(ty * 8 + i) * H_ + tx * 8;
    float4 r0 = make_float4(acc[i][0]+bv[0], acc[i][1]+bv[1], acc[i][2]+bv[2], acc[i][3]+bv[3]);
    float4 r1 = make_float4(acc[i][4]+bv[4], acc[i][5]+bv[5], acc[i][6]+bv[6], acc[i][7]+bv[7]);
    *(float4*)dst       = r0;
    *(float4*)(dst + 4) = r1;
  }
}

// ---------------- NT GEMM fp32, deterministic split-K (layer-1 proj) ----------
__global__ __launch_bounds__(256, 2)
void k_gemm_nt_splitk(float* __restrict__ part,
                      const float* __restrict__ A, int lda,
                      const float* __restrict__ Bt, int ldb,
                      int Kchunk)
{
  __shared__ float As[GBK][GBM + 4];
  __shared__ float Bs[GBK][GBN + 4];
  int bx = blockIdx.x;
  int mt = bx & 3;           // 512/128
  int nt = (bx >> 2) & 15;   // 2048/128
  int kc = bx >> 6;
  const float* Ap = A  + (long)mt * GBM * lda + (long)kc * Kchunk;
  const float* Bp = Bt + (long)nt * GBN * ldb + (long)kc * Kchunk;

  int tid = threadIdx.x;
  int tx = tid & 15, ty = tid >> 4;
  int am = tid >> 1, ak = (tid & 1) * 8;

  float acc[8][8];
  #pragma unroll
  for (int i = 0; i < 8; ++i)
    #pragma unroll
    for (int j = 0; j < 8; ++j) acc[i][j] = 0.f;

  for (int k0 = 0; k0 < Kchunk; k0 += GBK) {
    float4 a0 = *(const float4*)(Ap + (long)am * lda + k0 + ak);
    float4 a1 = *(const float4*)(Ap + (long)am * lda + k0 + ak + 4);
    float4 b0 = *(const float4*)(Bp + (long)am * ldb + k0 + ak);
    float4 b1 = *(const float4*)(Bp + (long)am * ldb + k0 + ak + 4);
    As[ak+0][am] = a0.x; As[ak+1][am] = a0.y; As[ak+2][am] = a0.z; As[ak+3][am] = a0.w;
    As[ak+4][am] = a1.x; As[ak+5][am] = a1.y; As[ak+6][am] = a1.z; As[ak+7][am] = a1.w;
    Bs[ak+0][am] = b0.x; Bs[ak+1][am] = b0.y; Bs[ak+2][am] = b0.z; Bs[ak+3][am] = b0.w;
    Bs[ak+4][am] = b1.x; Bs[ak+5][am] = b1.y; Bs[ak+6][am] = b1.z; Bs[ak+7][am] = b1.w;
    __syncthreads();
    #pragma unroll
    for (int kk = 0; kk < GBK; ++kk) {
      float a[8], b[8];
      *(float4*)&a[0] = *(const float4*)&As[kk][ty * 8];
      *(float4*)&a[4] = *(const float4*)&As[kk][ty * 8 + 4];
      *(float4*)&b[0] = *(const float4*)&Bs[kk][tx * 8];
      *(float4*)&b[4] = *(const float4*)&Bs[kk][tx * 8 + 4];
      #pragma unroll
      for (int i = 0; i < 8; ++i)
        #pragma unroll
        for (int j = 0; j < 8; ++j)
          acc[i][j] = fmaf(a[i], b[j], acc[i][j]);
    }
    __syncthreads();
  }
  float* base = part + (long)kc * (BT_ * G4_);
  #pragma unroll
  for (int i = 0; i < 8; ++i) {
    float* dst = base + (long)(mt * GBM + ty * 8 + i) * G4_ + nt * GBN + tx * 8;
    float4 r0 = make_float4(acc[i][0], acc[i][1], acc[i][2], acc[i][3]);
    float4 r1 = make_float4(acc[i][4], acc[i][5], acc[i][6], acc[i][7]);
    *(float4*)dst       = r0;
    *(float4*)(dst + 4) = r1;
  }
}

// ---------------- fp32 -> bf16 conversion (8 elems/thread) ----------------
__global__ __launch_bounds__(256)
void k_cvt_bf16(const float* __restrict__ src, unsigned short* __restrict__ dst) {
  long i = (long)blockIdx.x * 256 + threadIdx.x;     // i indexes groups of 8
  const float4* s = (const float4*)src + i * 2;
  float4 v0 = s[0], v1 = s[1];
  uint4 o;
  o.x = pk2_(v0.x, v0.y);
  o.y = pk2_(v0.z, v0.w);
  o.z = pk2_(v1.x, v1.y);
  o.w = pk2_(v1.z, v1.w);
  ((uint4*)dst)[i] = o;
}

// ---------------- bf16 MFMA NT GEMM: LSTM-0 input projection --------------
// part[kc][512][2048] += A_bf16[512][65536] @ W_fp32[2048][65536]^T (chunk kc)
// W converted to bf16 on the fly in registers. Tile 256x128, BK=32, 512 thr.
// grid: bx = mt + 2*nt + 32*kc ; mt in {0,1}, nt in [0,16), kc in [0,16)
#define PBM 256
#define PBN 128
#define PBK 32
#define PKCH 4096     // 65536/16
#define PNS  128      // PKCH/PBK

__global__ __launch_bounds__(512)
void k_proj_mfma(float* __restrict__ part,
                 const unsigned short* __restrict__ Aq,  // [512][65536] bf16
                 const float* __restrict__ Wf)           // [2048][65536] fp32
{
  // 64 B rows, XOR-swizzled: byte = (row*64 + slot*16) ^ ((row&7)<<4)
  __shared__ __align__(16) unsigned short As[2][PBM * PBK];  // 16 KB each
  __shared__ __align__(16) unsigned short Bs[2][PBN * PBK];  // 8 KB each
  int bx = blockIdx.x;
  int mt = bx & 1, nt = (bx >> 1) & 15, kc = bx >> 5;

  int tid  = threadIdx.x;
  int lane = tid & 63, wid = tid >> 6;
  int wm = wid & 3, wn = wid >> 2;        // 4 waves in M, 2 in N
  int fr = lane & 15, kg = lane >> 4;     // fragment row/col + k-slot

  // ---- staging assignment ----
  int arow = tid >> 1;                    // 0..255
  int as0  = (tid & 1) * 2;               // first of two 16B slots
  int brow = tid >> 2;                    // 0..127
  int bq   = tid & 3;                     // 16B slot

  const unsigned short* aptr = Aq + (((long)(mt * PBM + arow)) << 16) + kc * PKCH + as0 * 8;
  const float*          bptr = Wf + (((long)(nt * PBN + brow)) << 16) + kc * PKCH + bq * 8;

  int aw0 = (arow * 64 + (as0    ) * 16) ^ ((arow & 7) << 4);
  int aw1 = (arow * 64 + (as0 + 1) * 16) ^ ((arow & 7) << 4);
  int bw  = (brow * 64 + (bq     ) * 16) ^ ((brow & 7) << 4);

  // ---- fragment read offsets (swizzle constant = (fr&7)<<4) ----
  int abase = ((wm * 64 + fr) * 64 + kg * 16) ^ ((fr & 7) << 4);
  int bbase = ((wn * 64 + fr) * 64 + kg * 16) ^ ((fr & 7) << 4);

  f32x4 acc[4][4];
  #pragma unroll
  for (int i = 0; i < 4; ++i)
    #pragma unroll
    for (int j = 0; j < 4; ++j) acc[i][j] = (f32x4){0.f, 0.f, 0.f, 0.f};

  // ---- prologue: stage step 0 ----
  {
    uint4 a0 = *(const uint4*)(aptr);
    uint4 a1 = *(const uint4*)(aptr + 8);
    float4 b0 = *(const float4*)(bptr);
    float4 b1 = *(const float4*)(bptr + 4);
    uint4 pkv;
    pkv.x = pk2_(b0.x, b0.y); pkv.y = pk2_(b0.z, b0.w);
    pkv.z = pk2_(b1.x, b1.y); pkv.w = pk2_(b1.z, b1.w);
    *(uint4*)((char*)As[0] + aw0) = a0;
    *(uint4*)((char*)As[0] + aw1) = a1;
    *(uint4*)((char*)Bs[0] + bw)  = pkv;
  }
  __syncthreads();

  int cur = 0;
  for (int s = 0; s < PNS; ++s) {
    uint4 na0, na1; float4 nb0, nb1;
    if (s + 1 < PNS) {
      const unsigned short* ap = aptr + (s + 1) * PBK;
      na0 = *(const uint4*)(ap);
      na1 = *(const uint4*)(ap + 8);
      const float* bp = bptr + (s + 1) * PBK;
      nb0 = *(const float4*)(bp);
      nb1 = *(const float4*)(bp + 4);
    }
    // ---- compute on buf[cur] ----
    const char* ab = (const char*)As[cur];
    const char* bb = (const char*)Bs[cur];
    bf16x8 af[4], bfr[4];
    #pragma unroll
    for (int mf = 0; mf < 4; ++mf) af[mf]  = *(const bf16x8*)(ab + abase + mf * 1024);
    #pragma unroll
    for (int nf = 0; nf < 4; ++nf) bfr[nf] = *(const bf16x8*)(bb + bbase + nf * 1024);
    #pragma unroll
    for (int mf = 0; mf < 4; ++mf)
      #pragma unroll
      for (int nf = 0; nf < 4; ++nf)
        acc[mf][nf] = __builtin_amdgcn_mfma_f32_16x16x32_bf16(af[mf], bfr[nf], acc[mf][nf], 0, 0, 0);

    if (s + 1 < PNS) {
      uint4 pkv;
      pkv.x = pk2_(nb0.x, nb0.y); pkv.y = pk2_(nb0.z, nb0.w);
      pkv.z = pk2_(nb1.x, nb1.y); pkv.w = pk2_(nb1.z, nb1.w);
      char* aw = (char*)As[cur ^ 1];
      char* bwp = (char*)Bs[cur ^ 1];
      *(uint4*)(aw + aw0) = na0;
      *(uint4*)(aw + aw1) = na1;
      *(uint4*)(bwp + bw) = pkv;
    }
    __syncthreads();
    cur ^= 1;
  }

  // ---- epilogue: C/D mapping col=lane&15, row=(lane>>4)*4+reg ----
  float* base = part + (long)kc * (BT_ * G4_);
  int r0 = mt * PBM + wm * 64 + kg * 4;
  int cc = nt * PBN + wn * 64 + fr;
  #pragma unroll
  for (int mf = 0; mf < 4; ++mf)
    #pragma unroll
    for (int nf = 0; nf < 4; ++nf)
      #pragma unroll
      for (int j = 0; j < 4; ++j)
        base[(long)(r0 + mf * 16 + j) * G4_ + cc + nf * 16] = acc[mf][nf][j];
}

__global__ void k_reduce_gates(float* __restrict__ G, const float* __restrict__ part,
                               const float* __restrict__ b1, const float* __restrict__ b2,
                               int nchunk) {
  int idx = blockIdx.x * 256 + threadIdx.x;   // 512*2048
  int g = idx & (G4_ - 1);
  float s = b1[g] + b2[g];
  for (int p = 0; p < nchunk; ++p) s += part[(long)p * (BT_ * G4_) + idx];
  G[idx] = s;
}

// ---------------- GraphNorm (+ residual + ReLU), stats over B=16 ----------------
__global__ __launch_bounds__(256)
void k_graphnorm(float* out, const float* pre, const float* resid,
                 const float* __restrict__ wgt, const float* __restrict__ bias,
                 const float* __restrict__ ms)
{
  int idx = blockIdx.x * 256 + threadIdx.x;   // over T*N*H
  int h = idx & 127;
  float v[16];
  float mean = 0.f;
  #pragma unroll
  for (int bb = 0; bb < 16; ++bb) { v[bb] = pre[(long)bb * TNH_ + idx]; mean += v[bb]; }
  mean *= (1.f / 16.f);
  float msh = ms[h];
  float var = 0.f;
  #pragma unroll
  for (int bb = 0; bb < 16; ++bb) { v[bb] -= msh * mean; var += v[bb] * v[bb]; }
  var *= (1.f / 16.f);
  float sc = wgt[h] * rsqrtf(var + EPS_);
  float bh = bias[h];
  #pragma unroll
  for (int bb = 0; bb < 16; ++bb) {
    float r = sc * v[bb] + bh + resid[(long)bb * TNH_ + idx];
    out[(long)bb * TNH_ + idx] = fmaxf(r, 0.f);
  }
}

// ---------------- LSTM ----------------
__global__ void k_transpose_whh(const float* __restrict__ W, float* __restrict__ WT) {
  int idx = blockIdx.x * 256 + threadIdx.x;   // 512*2048
  int k = idx >> 11, g = idx & (G4_ - 1);
  WT[idx] = W[(long)g * HL_ + k];             // WT[k][g] = W[g][k]
}

__global__ __launch_bounds__(512)
void k_lstm_layer(const float* __restrict__ G,   // [B*T][2048] x-proj + bih + bhh
                  const float* __restrict__ WT,  // [512][2048]
                  float* __restrict__ y)         // [B][T][512]
{
  __shared__ float hs[HL_];
  __shared__ float gs[G4_];
  int b   = blockIdx.x;
  int tid = threadIdx.x;
  int g   = tid >> 7;
  int jq  = (tid & 127) << 2;
  const float* wp = WT + g * HL_ + jq;

  float c0 = 0.f, c1 = 0.f, c2 = 0.f, c3 = 0.f;   // used by tid<128 only
  hs[tid & 511] = 0.f;
  __syncthreads();

  for (int t = 0; t < T_; ++t) {
    const float* g0 = G + ((long)b * T_ + t) * G4_;
    float4 acc = *(const float4*)(g0 + g * HL_ + jq);
    #pragma unroll 8
    for (int k = 0; k < HL_; ++k) {
      float hk = hs[k];
      float4 wv = *(const float4*)(wp + (long)k * G4_);
      acc.x = fmaf(hk, wv.x, acc.x);
      acc.y = fmaf(hk, wv.y, acc.y);
      acc.z = fmaf(hk, wv.z, acc.z);
      acc.w = fmaf(hk, wv.w, acc.w);
    }
    __syncthreads();                       // all hs reads of this step done
    *(float4*)&gs[g * HL_ + jq] = acc;
    __syncthreads();                       // gates visible
    if (tid < 128) {
      int j = tid << 2;
      float4 ai = *(const float4*)&gs[0 * HL_ + j];
      float4 af = *(const float4*)&gs[1 * HL_ + j];
      float4 ag = *(const float4*)&gs[2 * HL_ + j];
      float4 ao = *(const float4*)&gs[3 * HL_ + j];
      float h0, h1, h2, h3;
      c0 = sigmoidf_(af.x) * c0 + sigmoidf_(ai.x) * tanhf(ag.x);
      h0 = sigmoidf_(ao.x) * tanhf(c0);
      c1 = sigmoidf_(af.y) * c1 + sigmoidf_(ai.y) * tanhf(ag.y);
      h1 = sigmoidf_(ao.y) * tanhf(c1);
      c2 = sigmoidf_(af.z) * c2 + sigmoidf_(ai.z) * tanhf(ag.z);
      h2 = sigmoidf_(ao.z) * tanhf(c2);
      c3 = sigmoidf_(af.w) * c3 + sigmoidf_(ai.w) * tanhf(ag.w);
      h3 = sigmoidf_(ao.w) * tanhf(c3);
      float4 hv = make_float4(h0, h1, h2, h3);
      *(float4*)&hs[j] = hv;
      *(float4*)(y + ((long)b * T_ + t) * HL_ + j) = hv;
    }
    __syncthreads();                       // hs(t) ready for next step
  }
}

__global__ void k_final(const float* __restrict__ y1, const float* __restrict__ Wp,
                        const float* __restrict__ bp, float* __restrict__ out) {
  int tid = threadIdx.x;      // 128 = 16 b * 8 o
  int b = tid >> 3, o = tid & 7;
  const float* h = y1 + ((long)b * T_ + (T_ - 1)) * HL_;
  const float* w = Wp + (long)o * HL_;
  float s = bp[o];
  for (int k = 0; k < HL_; ++k) s = fmaf(h[k], w[k], s);
  out[b * 8 + o] = s;
}

// ---------------- launch ----------------
extern "C" void kernel_launch(void* const* d_in, const int* in_sizes, int n_in,
                              void* d_out, int out_size, void* d_ws, size_t ws_size,
                              hipStream_t stream)
{
  const float* x    = (const float*)d_in[0];
  const float* adj  = (const float*)d_in[1];
  const float* W1   = (const float*)d_in[2];
  const float* b1   = (const float*)d_in[3];
  const float* W2   = (const float*)d_in[4];
  const float* b2   = (const float*)d_in[5];
  const float* gn1w = (const float*)d_in[6];
  const float* gn1b = (const float*)d_in[7];
  const float* gn1m = (const float*)d_in[8];
  const float* gn2w = (const float*)d_in[9];
  const float* gn2b = (const float*)d_in[10];
  const float* gn2m = (const float*)d_in[11];
  const float* Wih0 = (const float*)d_in[12];
  const float* Whh0 = (const float*)d_in[13];
  const float* bih0 = (const float*)d_in[14];
  const float* bhh0 = (const float*)d_in[15];
  const float* Wih1 = (const float*)d_in[16];
  const float* Whh1 = (const float*)d_in[17];
  const float* bih1 = (const float*)d_in[18];
  const float* bhh1 = (const float*)d_in[19];
  const float* Wp   = (const float*)d_in[20];
  const float* bp   = (const float*)d_in[21];
  float* out = (float*)d_out;

  // -------- workspace layout: 280.0 MB total --------
  float* w = (float*)d_ws;
  float* Mn  = w; w += 262144;    // [N][N]
  float* dv  = w; w += 512;
  float* G0  = w; w += 1048576;   // [BT][2048]
  float* G1  = w; w += 1048576;
  float* y0  = w; w += 262144;    // [B][T][HL]
  float* y1  = w; w += 262144;
  float* c0  = w; w += 8192;      // unused (layout stability)
  float* c1  = w; w += 8192;
  float* P   = w; w += 33554432;  // [B][T][N][H]
  float* Q   = w; w += 33554432;  // [B][T][N][H]
  (void)c0; (void)c1;
  // After GCN: P (h1) dead -> Qb (bf16 copy of Q, 67 MB) lives in P-space.
  unsigned short* Qb = (unsigned short*)P;
  // After k_cvt: Q (fp32 h2) dead -> partials + transposed weights in Q-space.
  float* Gp  = Q;                 // [16][512][2048] split-K partials (64 MB)
  float* WT0 = Q + 16777216;      // [512][2048]
  float* WT1 = Q + 17825792;      // [512][2048]

  // graph prep
  k_deg<<<N_, 64, 0, stream>>>(adj, dv);
  k_mnorm<<<1024, 256, 0, stream>>>(adj, dv, Mn);

  // GCN layer 1 (reassociated: M@(X@W) == (M@X)@W):
  k_gemm_nn<<<dim3(4, BT_), 256, 0, stream>>>(P, Mn, 0L, N_, x, (long)N_*C_, 0L, nullptr, N_);
  k_gemm_nn<<<dim3(4, BT_), 256, 0, stream>>>(P, P, (long)N_*H_, C_, W1, 0L, (long)C_*H_, b1, C_);
  k_graphnorm<<<8192, 256, 0, stream>>>(P, P, x, gn1w, gn1b, gn1m);

  // GCN layer 2
  k_gemm_nn<<<dim3(4, BT_), 256, 0, stream>>>(Q, Mn, 0L, N_, P, (long)N_*H_, 0L, nullptr, N_);
  k_gemm_nn<<<dim3(4, BT_), 256, 0, stream>>>(Q, Q, (long)N_*H_, H_, W2, 0L, (long)H_*H_, b2, H_);
  k_graphnorm<<<8192, 256, 0, stream>>>(Q, Q, P, gn2w, gn2b, gn2m);
  // ---- P dead -> write Qb (bf16) there; then Q dead -> Gp/WT live there ----

  k_cvt_bf16<<<16384, 256, 0, stream>>>(Q, Qb);        // h2 -> bf16
  k_transpose_whh<<<4096, 256, 0, stream>>>(Whh0, WT0);
  k_transpose_whh<<<4096, 256, 0, stream>>>(Whh1, WT1);

  // LSTM layer 0: bf16 MFMA input projection (split-K x16, deterministic) + fused recurrence
  k_proj_mfma<<<512, 512, 0, stream>>>(Gp, Qb, Wih0);
  k_reduce_gates<<<4096, 256, 0, stream>>>(G0, Gp, bih0, bhh0, 16);
  k_lstm_layer<<<16, 512, 0, stream>>>(G0, WT0, y0);

  // LSTM layer 1 (small, stays fp32)
  k_gemm_nt_splitk<<<256, 256, 0, stream>>>(Gp, y0, HL_, Wih1, HL_, HL_ / 4);
  k_reduce_gates<<<4096, 256, 0, stream>>>(G1, Gp, bih1, bhh1, 4);
  k_lstm_layer<<<16, 512, 0, stream>>>(G1, WT1, y1);

  k_final<<<1, 128, 0, stream>>>(y1, Wp, bp, out);
}